// Round 8
// baseline (134.953 us; speedup 1.0000x reference)
//
#include <hip/hip_runtime.h>
#include <stdint.h>

// ChiSquareLoss: per-image RGB 256-bin histograms of two [B,3,512,512] f32
// tensors, normalized, chi-square over 768 bins, mean over batch.
//
// R7: DS-pipe path split + chi fusion.
//  - Measured: LDS atomic ~32 cyc/wave-instr (R0-R2, layout-invariant, 41us
//    floor); non-atomic ds ops ~5.8 cyc (m134); HBM floor 33us. Pure-u8 (R5)
//    died on chain latency; pure-atomic is pipe-bound. SPLIT 50/50: even
//    float4s -> per-thread u8 hist (bank = tid&31, conflict-free, R5-validated
//    dedupe), odd float4s -> block-shared 256-bin LDS atomic hist. DS/CU =
//    49K (atomic) + 18K (u8) = 67K cyc < HBM 78K -> HBM-bound.
//  - 128-thread blocks, 34KB LDS -> 4 blocks/CU. Block = quarter-channel.
//    2 epochs x 128 u8-path elems/thread -> u8 counters provably safe.
//  - chi fused via tail-block: threadfence + done counter; last block loads
//    ghist with agent-scope atomics (device-coherent) and reduces. Saves the
//    chi launch + standalone small-kernel latency.

#define NCH      3
#define BINS     256
#define CBINS    (NCH * BINS)     // 768
#define THREADS  128
#define U8_WORDS 8192             // (BINS/4) pages x 128 words = 32 KB
#define AH_BASE  8192             // 256-word block atomic hist
#define ST_BASE  8448             // 256-word stage
#define LDS_WORDS 8704            // 34816 B
#define EPOCHS   2
#define GROUPS   8                // prefetch groups per epoch
#define GF4      8                // float4 per group per thread

__global__ __launch_bounds__(THREADS, 2)
void fused_kernel(const float* __restrict__ in0,
                  const float* __restrict__ in1,
                  unsigned int* __restrict__ ghist,   // [2][B][768]
                  unsigned int* __restrict__ done,
                  float* __restrict__ out, int B) {
    __shared__ uint32_t lds[LDS_WORDS];
    __shared__ int last;
    __shared__ double wsum[2];
    unsigned char* const hb = (unsigned char*)lds;
    uint32_t* const ahist = lds + AH_BASE;
    uint32_t* const stage = lds + ST_BASE;

    const int tid = threadIdx.x;
    const int bid = blockIdx.x;
    // grid 2*B*12: input x img x ch x seg (exact division — R5 lesson)
    const int bpin  = B * 12;
    const int input = bid / bpin;
    const int r     = bid - input * bpin;
    const int img   = r / 12;
    const int r2    = r - img * 12;
    const int ch    = r2 >> 2;
    const int seg   = r2 & 3;

    const float4* __restrict__ src = (const float4*)(input ? in1 : in0)
        + (size_t)img * 196608 + (size_t)ch * 65536 + (size_t)seg * 16384;

    const uint32_t hbase = (uint32_t)(tid << 2);
    unsigned int* const gh = &ghist[((size_t)(input * B + img) * NCH + ch) * BINS];

    for (int e = 0; e < EPOCHS; ++e) {
        // prefetch group 0 before zeroing (vmcnt overlaps LDS zero)
        float4 va[GF4], vb[GF4];
        #pragma unroll
        for (int j = 0; j < GF4; ++j)
            va[j] = src[(e * 64 + j) * THREADS + tid];

        // zero u8 hist (2048 uint4 = 16/thread) + ahist (64 uint4)
        #pragma unroll
        for (int k = 0; k < 16; ++k)
            ((uint4*)lds)[tid + k * THREADS] = make_uint4(0u, 0u, 0u, 0u);
        if (tid < 64) ((uint4*)(lds + AH_BASE))[tid] = make_uint4(0u, 0u, 0u, 0u);
        __syncthreads();

        #pragma unroll
        for (int c = 0; c < GROUPS; ++c) {
            float4* cur = (c & 1) ? vb : va;
            float4* nxt = (c & 1) ? va : vb;
            if (c < GROUPS - 1) {
                #pragma unroll
                for (int j = 0; j < GF4; ++j)
                    nxt[j] = src[(e * 64 + (c + 1) * GF4 + j) * THREADS + tid];
            }
            #pragma unroll
            for (int q = 0; q < GF4; ++q) {
                const float4 v = cur[q];
                // truncation == floor for non-negative; med3 clamp handles 1.0
                const uint32_t b0 = (uint32_t)fminf(fmaxf(v.x * 255.0f, 0.0f), 255.0f);
                const uint32_t b1 = (uint32_t)fminf(fmaxf(v.y * 255.0f, 0.0f), 255.0f);
                const uint32_t b2 = (uint32_t)fminf(fmaxf(v.z * 255.0f, 0.0f), 255.0f);
                const uint32_t b3 = (uint32_t)fminf(fmaxf(v.w * 255.0f, 0.0f), 255.0f);
                if ((q & 1) == 0) {
                    // u8 private path: byte(tid,bin) = (tid<<2)+((bin&0xFC)<<7)+(bin&3)
                    // -> word (bin>>2)*128+tid -> bank tid&31 (2/bank, free).
                    const uint32_t a0 = hbase + ((b0 & 0xFCu) << 7) + (b0 & 3u);
                    const uint32_t a1 = hbase + ((b1 & 0xFCu) << 7) + (b1 & 3u);
                    const uint32_t a2 = hbase + ((b2 & 0xFCu) << 7) + (b2 & 3u);
                    const uint32_t a3 = hbase + ((b3 & 0xFCu) << 7) + (b3 & 3u);
                    const uint32_t r0 = hb[a0];
                    const uint32_t r1 = hb[a1];
                    const uint32_t r2v = hb[a2];
                    const uint32_t r3 = hb[a3];
                    const uint32_t e1 = (b1 == b0);
                    const uint32_t e2 = (uint32_t)(b2 == b0) + (uint32_t)(b2 == b1);
                    const uint32_t e3 = (uint32_t)(b3 == b0) + (uint32_t)(b3 == b1) + (uint32_t)(b3 == b2);
                    hb[a0] = (unsigned char)(r0 + 1u);
                    hb[a1] = (unsigned char)(r1 + 1u + e1);
                    hb[a2] = (unsigned char)(r2v + 1u + e2);
                    hb[a3] = (unsigned char)(r3 + 1u + e3);
                } else {
                    // atomic path: block-shared 256-bin hist
                    atomicAdd(&ahist[b0], 1u);
                    atomicAdd(&ahist[b1], 1u);
                    atomicAdd(&ahist[b2], 1u);
                    atomicAdd(&ahist[b3], 1u);
                }
            }
        }
        __syncthreads();

        // flush phase 1: u8 column sums. thread t: page p=t>>1, half h=t&1;
        // rotation (j+t)&63 keeps banks 2-way. u16 SWAR lanes max 64*255.
        {
            const int p = tid >> 1, h = tid & 1;
            const uint32_t* pg = lds + p * THREADS + h * 64;
            uint32_t accE = 0, accO = 0;
            #pragma unroll 8
            for (int j = 0; j < 64; ++j) {
                const uint32_t x = pg[(j + tid) & 63];
                accE += x & 0x00FF00FFu;
                accO += (x >> 8) & 0x00FF00FFu;
            }
            stage[tid * 2]     = accE;   // u16: bins 4p+0 (lo), 4p+2 (hi)
            stage[tid * 2 + 1] = accO;   // u16: bins 4p+1 (lo), 4p+3 (hi)
        }
        __syncthreads();

        // flush phase 2: bins tid and tid+128; add ahist + 2 half partials.
        #pragma unroll
        for (int k = 0; k < 2; ++k) {
            const int b   = tid + k * THREADS;
            const int p   = b >> 2;
            const int sel = b & 1;
            const int sh  = ((b >> 1) & 1) * 16;
            uint32_t s = ahist[b];
            #pragma unroll
            for (int h = 0; h < 2; ++h)
                s += (stage[(p * 2 + h) * 2 + sel] >> sh) & 0xFFFFu;
            atomicAdd(&gh[b], s);
        }
        __syncthreads();   // phase2 reads ahist/stage; next epoch re-zeroes
    }

    // ---- fused chi: last block to flush computes the reduction ----
    __threadfence();
    if (tid == 0)
        last = (atomicAdd(done, 1u) == (unsigned)(gridDim.x - 1));
    __syncthreads();
    if (!last) return;
    __threadfence();

    const float invN = 1.0f / 786432.0f;   // per-image sum is exactly 786432
    double acc = 0.0;
    const int total = B * CBINS;
    for (int i = tid; i < total; i += THREADS) {
        const uint32_t c1 = __hip_atomic_load(&ghist[i],
            __ATOMIC_RELAXED, __HIP_MEMORY_SCOPE_AGENT);
        const uint32_t c2 = __hip_atomic_load(&ghist[i + total],
            __ATOMIC_RELAXED, __HIP_MEMORY_SCOPE_AGENT);
        const float d = (float)((int)c1 - (int)c2) * invN;   // exact int diff
        const float s = (float)(c1 + c2) * invN + 1e-10f;
        acc += (double)(d * d / s);
    }
    #pragma unroll
    for (int off = 32; off > 0; off >>= 1)
        acc += __shfl_down(acc, off);
    if ((tid & 63) == 0) wsum[tid >> 6] = acc;
    __syncthreads();
    if (tid == 0)
        out[0] = (float)((wsum[0] + wsum[1]) / (double)B);
}

extern "C" void kernel_launch(void* const* d_in, const int* in_sizes, int n_in,
                              void* d_out, int out_size, void* d_ws, size_t ws_size,
                              hipStream_t stream) {
    const float* in0 = (const float*)d_in[0];
    const float* in1 = (const float*)d_in[1];
    const int B = in_sizes[0] / (NCH * 512 * 512);   // 32

    unsigned int* ghist = (unsigned int*)d_ws;
    unsigned int* done  = ghist + (size_t)2 * B * CBINS;
    const size_t zero_bytes = ((size_t)2 * B * CBINS + 1) * sizeof(unsigned int);
    const int grid = 2 * B * 12;                     // 768

    hipMemsetAsync(d_ws, 0, zero_bytes, stream);
    fused_kernel<<<grid, THREADS, 0, stream>>>(in0, in1, ghist, done,
                                               (float*)d_out, B);
}